// Round 1
// baseline (741.207 us; speedup 1.0000x reference)
//
#include <hip/hip_runtime.h>
#include <hip/hip_bf16.h>
#include <stdint.h>

// Problem constants (match setup_inputs)
#define M_ROWS 100352   // 2048 * 49
#define C_DIM  512
#define QKV_N  1536
#define NH     16
#define HD     32
#define NWIN   49       // window tokens (7*7)
#define NMASK  64

typedef __attribute__((ext_vector_type(4))) float        f32x4;
typedef __attribute__((ext_vector_type(8))) short        bf16x8;
typedef __attribute__((ext_vector_type(4))) unsigned int u32x4;

static __device__ __forceinline__ unsigned short f32_to_bf16(float f) {
  union { float f; unsigned int u; } v; v.f = f;
  unsigned int u = v.u;
  return (unsigned short)((u + 0x7FFFu + ((u >> 16) & 1u)) >> 16);  // RNE
}

// global -> LDS direct DMA, 16B per lane. dest = wave-uniform base + lane*16.
static __device__ __forceinline__ void gload_lds16(const void* g, void* l) {
  __builtin_amdgcn_global_load_lds(
      (const __attribute__((address_space(1))) unsigned int*)g,
      (__attribute__((address_space(3))) unsigned int*)l, 16, 0, 0);
}

// ---------------------------------------------------------------- k_cvt
__global__ void k_cvt(const float* __restrict__ in, unsigned short* __restrict__ out, int n4) {
  int i = blockIdx.x * blockDim.x + threadIdx.x;
  int stride = gridDim.x * blockDim.x;
  for (; i < n4; i += stride) {
    float4 v = ((const float4*)in)[i];
    ushort4 o = make_ushort4(f32_to_bf16(v.x), f32_to_bf16(v.y),
                             f32_to_bf16(v.z), f32_to_bf16(v.w));
    ((ushort4*)out)[i] = o;
  }
}

// ------------------------------------------- transpose + convert weights
// in: K x N f32 (row-major), out: N x K bf16 (row-major) == B^T
__global__ void k_transpose_cvt(const float* __restrict__ in, unsigned short* __restrict__ out,
                                int K, int N) {
  __shared__ float t[32][33];
  const int n0 = blockIdx.x * 32, k0 = blockIdx.y * 32;
  const int tx = threadIdx.x & 31, ty = threadIdx.x >> 5;  // 32 x 8
#pragma unroll
  for (int rr = 0; rr < 32; rr += 8)
    t[ty + rr][tx] = in[(size_t)(k0 + ty + rr) * N + n0 + tx];
  __syncthreads();
#pragma unroll
  for (int rr = 0; rr < 32; rr += 8)
    out[(size_t)(n0 + ty + rr) * K + k0 + tx] = f32_to_bf16(t[tx][ty + rr]);
}

// ------------------------------------------------------- rel-pos bias table
// btab[h][i][j] = table[rpi(i,j)*16 + h],  rpi = ((j/7) - (i/7) + 6) * 13
__global__ void k_bias_tab(const float* __restrict__ table, float* __restrict__ bt) {
  int idx = blockIdx.x * blockDim.x + threadIdx.x;
  if (idx >= NH * NWIN * NWIN) return;
  int h = idx / (NWIN * NWIN), rem = idx % (NWIN * NWIN);
  int i = rem / NWIN, j = rem % NWIN;
  int rpi = ((j / 7) - (i / 7) + 6) * 13;
  bt[idx] = table[rpi * NH + h];
}

// ------------------------------------------------------------------ GEMM
// C[M,N] = A[M,K](bf16) * BT[N,K]^T(bf16) + bias[N].  m97 structure:
// 128x128 tile, BK=32, 4 waves (2x2), each wave 64x64 = 4x4 frags 16x16x32.
template <int OUT_BF16>
__global__ __launch_bounds__(256) void k_gemm(const unsigned short* __restrict__ A,
                                              const unsigned short* __restrict__ BT,
                                              const float* __restrict__ bias,
                                              void* __restrict__ Cout,
                                              int M, int N, int K) {
  __shared__ __align__(16) unsigned short lA[128 * 32];
  __shared__ __align__(16) unsigned short lB[128 * 32];
  const int tid = threadIdx.x;
  const int lane = tid & 63, wave = tid >> 6;
  const int wr = wave >> 1, wc = wave & 1;
  const int lr = lane & 15, lg = lane >> 4;
  const int m0 = blockIdx.y * 128, n0 = blockIdx.x * 128;

  const f32x4 fz = {0.f, 0.f, 0.f, 0.f};
  f32x4 acc[4][4];
#pragma unroll
  for (int i = 0; i < 4; ++i)
#pragma unroll
    for (int j = 0; j < 4; ++j) acc[i][j] = fz;

  const int cb = wave * 128;  // this wave's staging chunk base (of 512 16B-chunks)
  for (int kt = 0; kt < K; kt += 32) {
#pragma unroll
    for (int i = 0; i < 2; ++i) {
      const int chunk = cb + i * 64 + lane;
      const int row = chunk >> 2, kc = chunk & 3;
      gload_lds16(A + (size_t)(m0 + row) * K + kt + kc * 8, lA + (cb + i * 64) * 8);
      gload_lds16(BT + (size_t)(n0 + row) * K + kt + kc * 8, lB + (cb + i * 64) * 8);
    }
    __syncthreads();  // drains vmcnt -> LDS tiles valid
    bf16x8 af[4], bfr[4];
#pragma unroll
    for (int mi = 0; mi < 4; ++mi)
      af[mi] = *(const bf16x8*)(lA + (wr * 64 + mi * 16 + lr) * 32 + lg * 8);
#pragma unroll
    for (int nj = 0; nj < 4; ++nj)
      bfr[nj] = *(const bf16x8*)(lB + (wc * 64 + nj * 16 + lr) * 32 + lg * 8);
#pragma unroll
    for (int mi = 0; mi < 4; ++mi)
#pragma unroll
      for (int nj = 0; nj < 4; ++nj)
        acc[mi][nj] = __builtin_amdgcn_mfma_f32_16x16x32_bf16(af[mi], bfr[nj], acc[mi][nj], 0, 0, 0);
    __syncthreads();  // all waves done reading before next stage overwrites
  }

  float bv[4];
#pragma unroll
  for (int nj = 0; nj < 4; ++nj) bv[nj] = bias[n0 + wc * 64 + nj * 16 + lr];
#pragma unroll
  for (int mi = 0; mi < 4; ++mi)
#pragma unroll
    for (int nj = 0; nj < 4; ++nj)
#pragma unroll
      for (int r = 0; r < 4; ++r) {
        const int row = m0 + wr * 64 + mi * 16 + 4 * lg + r;  // C/D: row=4g+reg
        const int col = n0 + wc * 64 + nj * 16 + lr;          //      col=lane&15
        const float v = acc[mi][nj][r] + bv[nj];
        if (OUT_BF16)
          ((unsigned short*)Cout)[(size_t)row * N + col] = f32_to_bf16(v);
        else
          ((float*)Cout)[(size_t)row * N + col] = v;
      }
}

// ------------------------------------------------------------- attention
// One wave per (window b, head h). qkv: [M,1536] bf16 (q|k|v each 512 cols).
// S = q*k^T (both operands row-major-in-d -> contiguous frags from global),
// softmax with bias+mask, P -> LDS bf16, V^T staged in LDS, O = P*V.
__global__ __launch_bounds__(64) void k_attn(const unsigned short* __restrict__ qkv,
                                             const float* __restrict__ mask,
                                             const float* __restrict__ btab,
                                             unsigned short* __restrict__ aout) {
  const int bh = blockIdx.x;
  const int b = bh >> 4, h = bh & 15;
  const int w = b & 63;
  const int lane = threadIdx.x;
  const int lr = lane & 15, lg = lane >> 4;

  __shared__ __align__(16) unsigned short Pl[64][72];  // pad 72: 2-way max on b128
  __shared__ __align__(16) unsigned short Vt[32][72];  // V^T[d][key]

  const unsigned short* qp = qkv + (size_t)b * NWIN * QKV_N + h * HD;
  const unsigned short* kp = qp + C_DIM;
  const unsigned short* vp = qp + 2 * C_DIM;

  // q/k fragments straight from global (rows 49..63 read in-ws garbage; masked below)
  bf16x8 qf[4], kf[4];
#pragma unroll
  for (int t = 0; t < 4; ++t) {
    qf[t] = *(const bf16x8*)(qp + (size_t)(t * 16 + lr) * QKV_N + lg * 8);
    kf[t] = *(const bf16x8*)(kp + (size_t)(t * 16 + lr) * QKV_N + lg * 8);
  }

  // stage V^T (keys >= 49 zeroed so padded P columns contribute exact 0)
  u32x4 zv = {0u, 0u, 0u, 0u};
#pragma unroll
  for (int c0 = 0; c0 < 256; c0 += 64) {
    const int c = c0 + lane;
    const int key = c >> 2, d0 = (c & 3) << 3;
    union { unsigned short s[8]; u32x4 v; } tmp;
    tmp.v = (key < NWIN) ? *(const u32x4*)(vp + (size_t)key * QKV_N + d0) : zv;
#pragma unroll
    for (int j = 0; j < 8; ++j) Vt[d0 + j][key] = tmp.s[j];
  }

  const f32x4 fz = {0.f, 0.f, 0.f, 0.f};
  f32x4 s[4][4];
#pragma unroll
  for (int mi = 0; mi < 4; ++mi)
#pragma unroll
    for (int nj = 0; nj < 4; ++nj) s[mi][nj] = fz;
#pragma unroll
  for (int mi = 0; mi < 4; ++mi)
#pragma unroll
    for (int nj = 0; nj < 4; ++nj)
      s[mi][nj] = __builtin_amdgcn_mfma_f32_16x16x32_bf16(qf[mi], kf[nj], s[mi][nj], 0, 0, 0);

  const float scale = 0.1767766952966369f;  // 32^-0.5
  const float* mrow = mask + (size_t)w * (NWIN * NWIN);
  const float* brow = btab + (size_t)h * (NWIN * NWIN);

  float inv_l[4][4];
#pragma unroll
  for (int mi = 0; mi < 4; ++mi) {
#pragma unroll
    for (int r = 0; r < 4; ++r) {
      const int i = mi * 16 + 4 * lg + r;  // this lane's S row
      float pv[4];
      float mmax = -1e30f;
#pragma unroll
      for (int nj = 0; nj < 4; ++nj) {
        const int j = nj * 16 + lr;
        float v = -1e30f;
        if (i < NWIN && j < NWIN)
          v = s[mi][nj][r] * scale + brow[i * NWIN + j] + mrow[i * NWIN + j];
        pv[nj] = v;
        mmax = fmaxf(mmax, v);
      }
#pragma unroll
      for (int mk = 1; mk < 16; mk <<= 1) mmax = fmaxf(mmax, __shfl_xor(mmax, mk, 64));
      float sum = 0.f;
#pragma unroll
      for (int nj = 0; nj < 4; ++nj) {
        const float p = __expf(pv[nj] - mmax);  // j>=49 -> exp(-inf) = exact 0
        pv[nj] = p;
        sum += p;
      }
#pragma unroll
      for (int mk = 1; mk < 16; mk <<= 1) sum += __shfl_xor(sum, mk, 64);
      inv_l[mi][r] = 1.f / sum;
#pragma unroll
      for (int nj = 0; nj < 4; ++nj)
        Pl[i][nj * 16 + lr] = f32_to_bf16(pv[nj]);
    }
  }
  __syncthreads();

  f32x4 o[4][2];
#pragma unroll
  for (int mi = 0; mi < 4; ++mi)
#pragma unroll
    for (int nj = 0; nj < 2; ++nj) o[mi][nj] = fz;
#pragma unroll
  for (int ks = 0; ks < 2; ++ks) {
    bf16x8 vf[2];
#pragma unroll
    for (int nj = 0; nj < 2; ++nj)
      vf[nj] = *(const bf16x8*)(&Vt[nj * 16 + lr][ks * 32 + lg * 8]);
#pragma unroll
    for (int mi = 0; mi < 4; ++mi) {
      const bf16x8 pf = *(const bf16x8*)(&Pl[mi * 16 + lr][ks * 32 + lg * 8]);
#pragma unroll
      for (int nj = 0; nj < 2; ++nj)
        o[mi][nj] = __builtin_amdgcn_mfma_f32_16x16x32_bf16(pf, vf[nj], o[mi][nj], 0, 0, 0);
    }
  }

#pragma unroll
  for (int mi = 0; mi < 4; ++mi)
#pragma unroll
    for (int r = 0; r < 4; ++r) {
      const int i = mi * 16 + 4 * lg + r;
      if (i < NWIN) {
#pragma unroll
        for (int nj = 0; nj < 2; ++nj) {
          const int col = h * HD + nj * 16 + lr;
          aout[(size_t)(b * NWIN + i) * C_DIM + col] =
              f32_to_bf16(o[mi][nj][r] * inv_l[mi][r]);
        }
      }
    }
}

// ---------------------------------------------------------------- launch
static const size_t SZ_QKV = (size_t)M_ROWS * QKV_N * 2;   // 308,281,344
static const size_t SZ_XB  = (size_t)M_ROWS * C_DIM * 2;   // 102,760,448
static const size_t SZ_WQ  = (size_t)QKV_N * C_DIM * 2;
static const size_t SZ_WP  = (size_t)C_DIM * C_DIM * 2;
static const size_t OFF_QKV = 0;
static const size_t OFF_XB  = OFF_QKV + SZ_QKV;   // x_bf16, later reused as attn_out
static const size_t OFF_WQ  = OFF_XB + SZ_XB;
static const size_t OFF_WP  = OFF_WQ + SZ_WQ;
static const size_t OFF_BT  = OFF_WP + SZ_WP;

extern "C" void kernel_launch(void* const* d_in, const int* in_sizes, int n_in,
                              void* d_out, int out_size, void* d_ws, size_t ws_size,
                              hipStream_t stream) {
  const float* x      = (const float*)d_in[0];
  const float* mask   = (const float*)d_in[1];
  const float* qkv_w  = (const float*)d_in[2];
  const float* qkv_b  = (const float*)d_in[3];
  const float* proj_w = (const float*)d_in[4];
  const float* proj_b = (const float*)d_in[5];
  const float* rel    = (const float*)d_in[6];
  float* out = (float*)d_out;

  char* ws = (char*)d_ws;
  unsigned short* qkvb = (unsigned short*)(ws + OFF_QKV);
  unsigned short* xb   = (unsigned short*)(ws + OFF_XB);
  unsigned short* wqT  = (unsigned short*)(ws + OFF_WQ);
  unsigned short* wpT  = (unsigned short*)(ws + OFF_WP);
  float*          btab = (float*)(ws + OFF_BT);

  k_cvt<<<2048, 256, 0, stream>>>(x, xb, M_ROWS * C_DIM / 4);
  k_transpose_cvt<<<dim3(QKV_N / 32, C_DIM / 32), 256, 0, stream>>>(qkv_w, wqT, C_DIM, QKV_N);
  k_transpose_cvt<<<dim3(C_DIM / 32, C_DIM / 32), 256, 0, stream>>>(proj_w, wpT, C_DIM, C_DIM);
  k_bias_tab<<<(NH * NWIN * NWIN + 255) / 256, 256, 0, stream>>>(rel, btab);

  // qkv = x @ qkv_w + qkv_b   (bf16 out)
  k_gemm<1><<<dim3(QKV_N / 128, M_ROWS / 128), 256, 0, stream>>>(
      xb, wqT, qkv_b, qkvb, M_ROWS, QKV_N, C_DIM);

  // attention -> attn_out (reuses xb region; x_bf16 no longer needed)
  k_attn<<<2048 * NH, 64, 0, stream>>>(qkvb, mask, btab, xb);

  // out = attn_out @ proj_w + proj_b  (f32 out)
  k_gemm<0><<<dim3(C_DIM / 128, M_ROWS / 128), 256, 0, stream>>>(
      xb, wpT, proj_b, out, M_ROWS, C_DIM, C_DIM);
}

// Round 2
// 617.120 us; speedup vs baseline: 1.2011x; 1.2011x over previous
//
#include <hip/hip_runtime.h>
#include <hip/hip_bf16.h>
#include <stdint.h>

// Problem constants (match setup_inputs)
#define M_ROWS 100352   // 2048 * 49
#define C_DIM  512
#define QKV_N  1536
#define NH     16
#define HD     32
#define NWIN   49       // window tokens (7*7)
#define NMASK  64

typedef __attribute__((ext_vector_type(4))) float        f32x4;
typedef __attribute__((ext_vector_type(8))) short        bf16x8;
typedef __attribute__((ext_vector_type(4))) unsigned int u32x4;
typedef unsigned short ushort_t;

static __device__ __forceinline__ unsigned short f32_to_bf16(float f) {
  union { float f; unsigned int u; } v; v.f = f;
  unsigned int u = v.u;
  return (unsigned short)((u + 0x7FFFu + ((u >> 16) & 1u)) >> 16);  // RNE
}

// global -> LDS direct DMA, 16B per lane. dest = wave-uniform base + lane*16.
static __device__ __forceinline__ void gload_lds16(const void* g, void* l) {
  __builtin_amdgcn_global_load_lds(
      (const __attribute__((address_space(1))) unsigned int*)g,
      (__attribute__((address_space(3))) unsigned int*)l, 16, 0, 0);
}

// ---------------------------------------------------------------- k_cvt
__global__ void k_cvt(const float* __restrict__ in, unsigned short* __restrict__ out, int n4) {
  int i = blockIdx.x * blockDim.x + threadIdx.x;
  int stride = gridDim.x * blockDim.x;
  for (; i < n4; i += stride) {
    float4 v = ((const float4*)in)[i];
    ushort4 o = make_ushort4(f32_to_bf16(v.x), f32_to_bf16(v.y),
                             f32_to_bf16(v.z), f32_to_bf16(v.w));
    ((ushort4*)out)[i] = o;
  }
}

// ------------------------------------------- transpose + convert weights
// in: K x N f32 (row-major), out: N x K bf16 (row-major) == B^T
__global__ void k_transpose_cvt(const float* __restrict__ in, unsigned short* __restrict__ out,
                                int K, int N) {
  __shared__ float t[32][33];
  const int n0 = blockIdx.x * 32, k0 = blockIdx.y * 32;
  const int tx = threadIdx.x & 31, ty = threadIdx.x >> 5;  // 32 x 8
#pragma unroll
  for (int rr = 0; rr < 32; rr += 8)
    t[ty + rr][tx] = in[(size_t)(k0 + ty + rr) * N + n0 + tx];
  __syncthreads();
#pragma unroll
  for (int rr = 0; rr < 32; rr += 8)
    out[(size_t)(n0 + ty + rr) * K + k0 + tx] = f32_to_bf16(t[tx][ty + rr]);
}

// ----------------------------------------- fused bias+mask table (padded)
// bmt[w][h][i][j] (64x16x64x64 f32) = mask[w][i][j] + bias[h][i][j], -1e30 pad.
__global__ __launch_bounds__(256) void k_bm(const float* __restrict__ mask,
                                            const float* __restrict__ rel,
                                            float* __restrict__ bmt) {
  const int idx = blockIdx.x * 256 + threadIdx.x;   // w<<16 | h<<12 | i<<6 | j
  const int j = idx & 63, i = (idx >> 6) & 63, h = (idx >> 12) & 15, w = idx >> 16;
  float v = -1e30f;
  if (i < NWIN && j < NWIN) {
    const int rpi = ((j / 7) - (i / 7) + 6) * 13;
    v = mask[w * (NWIN * NWIN) + i * NWIN + j] + rel[rpi * NH + h];
  }
  bmt[idx] = v;
}

// ------------------------------------------------------------------ GEMM
// C[M,N] = A[M,K](bf16) * BT[N,K]^T(bf16) + bias[N].  m97 structure.
template <int OUT_BF16>
__global__ __launch_bounds__(256) void k_gemm(const unsigned short* __restrict__ A,
                                              const unsigned short* __restrict__ BT,
                                              const float* __restrict__ bias,
                                              void* __restrict__ Cout,
                                              int M, int N, int K) {
  __shared__ __align__(16) unsigned short lA[128 * 32];
  __shared__ __align__(16) unsigned short lB[128 * 32];
  const int tid = threadIdx.x;
  const int lane = tid & 63, wave = tid >> 6;
  const int wr = wave >> 1, wc = wave & 1;
  const int lr = lane & 15, lg = lane >> 4;
  const int m0 = blockIdx.y * 128, n0 = blockIdx.x * 128;

  const f32x4 fz = {0.f, 0.f, 0.f, 0.f};
  f32x4 acc[4][4];
#pragma unroll
  for (int i = 0; i < 4; ++i)
#pragma unroll
    for (int j = 0; j < 4; ++j) acc[i][j] = fz;

  const int cb = wave * 128;
  for (int kt = 0; kt < K; kt += 32) {
#pragma unroll
    for (int i = 0; i < 2; ++i) {
      const int chunk = cb + i * 64 + lane;
      const int row = chunk >> 2, kc = chunk & 3;
      gload_lds16(A + (size_t)(m0 + row) * K + kt + kc * 8, lA + (cb + i * 64) * 8);
      gload_lds16(BT + (size_t)(n0 + row) * K + kt + kc * 8, lB + (cb + i * 64) * 8);
    }
    __syncthreads();
    bf16x8 af[4], bfr[4];
#pragma unroll
    for (int mi = 0; mi < 4; ++mi)
      af[mi] = *(const bf16x8*)(lA + (wr * 64 + mi * 16 + lr) * 32 + lg * 8);
#pragma unroll
    for (int nj = 0; nj < 4; ++nj)
      bfr[nj] = *(const bf16x8*)(lB + (wc * 64 + nj * 16 + lr) * 32 + lg * 8);
#pragma unroll
    for (int mi = 0; mi < 4; ++mi)
#pragma unroll
      for (int nj = 0; nj < 4; ++nj)
        acc[mi][nj] = __builtin_amdgcn_mfma_f32_16x16x32_bf16(af[mi], bfr[nj], acc[mi][nj], 0, 0, 0);
    __syncthreads();
  }

  float bv[4];
#pragma unroll
  for (int nj = 0; nj < 4; ++nj) bv[nj] = bias[n0 + wc * 64 + nj * 16 + lr];
#pragma unroll
  for (int mi = 0; mi < 4; ++mi)
#pragma unroll
    for (int nj = 0; nj < 4; ++nj)
#pragma unroll
      for (int r = 0; r < 4; ++r) {
        const int row = m0 + wr * 64 + mi * 16 + 4 * lg + r;
        const int col = n0 + wc * 64 + nj * 16 + lr;
        const float v = acc[mi][nj][r] + bv[nj];
        if (OUT_BF16)
          ((unsigned short*)Cout)[(size_t)row * N + col] = f32_to_bf16(v);
        else
          ((float*)Cout)[(size_t)row * N + col] = v;
      }
}

// ------------------------------------------------------------- attention
// 4 waves/block, one (b,h) per wave, zero barriers (waves independent).
// Swapped QK^T: S^T = mfma(K,Q) -> lane holds, per ni (query group), 16 j-vals
// of query i=16ni+lr -> in-register softmax + 2 shfl_xor.  P (scaled by 1/l,
// bf16) -> per-wave LDS half-tile [32][128B] with granule XOR swizzle.
// V^T staged in stride-66 LDS (conflict-free transposing writes).
__global__ __launch_bounds__(256) void k_attn(const unsigned short* __restrict__ qkv,
                                              const float* __restrict__ bmt,
                                              unsigned short* __restrict__ aout) {
  const int wave = threadIdx.x >> 6, lane = threadIdx.x & 63;
  const int lr = lane & 15, lg = lane >> 4;
  const int idx = blockIdx.x * 4 + wave;
  const int b = idx >> 4, h = idx & 15, w = b & 63;

  __shared__ __align__(16) unsigned short Pl[4][2048];  // [32 rows][64] swizzled
  __shared__ __align__(16) unsigned short Vt[4][2112];  // V^T, stride 66
  unsigned short* pl = Pl[wave];
  unsigned short* vt = Vt[wave];

  const unsigned short* qp = qkv + (size_t)b * NWIN * QKV_N + h * HD;
  const unsigned short* kp = qp + C_DIM;
  const unsigned short* vp = qp + 2 * C_DIM;

  // A = K frags, B = Q frags (rows 49..63 read in-ws garbage; masked by table)
  bf16x8 kf[4], qf[4];
#pragma unroll
  for (int t = 0; t < 4; ++t) {
    kf[t] = *(const bf16x8*)(kp + (size_t)(t * 16 + lr) * QKV_N + lg * 8);
    qf[t] = *(const bf16x8*)(qp + (size_t)(t * 16 + lr) * QKV_N + lg * 8);
  }

  // stage V^T (keys >= 49 zeroed), layout vt[d*66 + key]: conflict-free writes
  const u32x4 zv = {0u, 0u, 0u, 0u};
#pragma unroll
  for (int c0 = 0; c0 < 4; ++c0) {
    const int c = c0 * 64 + lane;
    const int key = c >> 2, d0 = (c & 3) << 3;
    union { u32x4 v; unsigned short s[8]; } tmp;
    tmp.v = (key < NWIN) ? *(const u32x4*)(vp + (size_t)key * QKV_N + d0) : zv;
#pragma unroll
    for (int jj = 0; jj < 8; ++jj) vt[(d0 + jj) * 66 + key] = tmp.s[jj];
  }

  // S^T[j][i] = sum_d K[j][d] Q[i][d]
  const f32x4 fz = {0.f, 0.f, 0.f, 0.f};
  f32x4 s[4][4];  // [mi = j-frag][ni = i-frag]
#pragma unroll
  for (int mi = 0; mi < 4; ++mi)
#pragma unroll
    for (int ni = 0; ni < 4; ++ni) s[mi][ni] = fz;
#pragma unroll
  for (int mi = 0; mi < 4; ++mi)
#pragma unroll
    for (int ni = 0; ni < 4; ++ni)
      s[mi][ni] = __builtin_amdgcn_mfma_f32_16x16x32_bf16(kf[mi], qf[ni], s[mi][ni], 0, 0, 0);

  // V^T B-frags (read once; stride-66 rows are 4B-aligned only -> 4 x b32)
  union VU { unsigned int u[4]; bf16x8 v; };
  VU vfr[2][2];  // [nj][ks]
#pragma unroll
  for (int nj = 0; nj < 2; ++nj)
#pragma unroll
    for (int ks = 0; ks < 2; ++ks) {
      const int base = ((16 * nj + lr) * 66 + 32 * ks + 8 * lg) >> 1;  // uint idx
#pragma unroll
      for (int u = 0; u < 4; ++u) vfr[nj][ks].u[u] = ((const unsigned int*)vt)[base + u];
    }

  const float scale = 0.1767766952966369f;  // 32^-0.5
  const float* tbl = bmt + ((size_t)(w * NH + h) << 12);

  f32x4 o[4][2];  // [qi][nj]
#pragma unroll
  for (int qi = 0; qi < 4; ++qi)
#pragma unroll
    for (int nj = 0; nj < 2; ++nj) o[qi][nj] = fz;

#pragma unroll
  for (int ni = 0; ni < 4; ++ni) {
    // softmax for queries i = 16*ni + lr over this lane's 16 j-values
    float v[16];
    float mx = -3e38f;
#pragma unroll
    for (int mi = 0; mi < 4; ++mi) {
      const f32x4 t4 = *(const f32x4*)(tbl + (16 * ni + lr) * 64 + 16 * mi + 4 * lg);
#pragma unroll
      for (int r = 0; r < 4; ++r) {
        v[mi * 4 + r] = fmaf(s[mi][ni][r], scale, t4[r]);
        mx = fmaxf(mx, v[mi * 4 + r]);
      }
    }
    mx = fmaxf(mx, __shfl_xor(mx, 16));
    mx = fmaxf(mx, __shfl_xor(mx, 32));
    float sum = 0.f;
#pragma unroll
    for (int t = 0; t < 16; ++t) {
      v[t] = __expf(v[t] - mx);
      sum += v[t];
    }
    sum += __shfl_xor(sum, 16);
    sum += __shfl_xor(sum, 32);
    const float inv = __builtin_amdgcn_rcpf(sum);

    // P row i -> pl row ip = 16*(ni&1)+lr, b64 writes, granule^=(row&7)
    const int ip = 16 * (ni & 1) + lr;
#pragma unroll
    for (int mi = 0; mi < 4; ++mi) {
      const unsigned int lo = (unsigned int)f32_to_bf16(v[mi * 4 + 0] * inv) |
                              ((unsigned int)f32_to_bf16(v[mi * 4 + 1] * inv) << 16);
      const unsigned int hi = (unsigned int)f32_to_bf16(v[mi * 4 + 2] * inv) |
                              ((unsigned int)f32_to_bf16(v[mi * 4 + 3] * inv) << 16);
      const int byteoff = 32 * mi + 8 * lg;
      const int sw = byteoff ^ ((ip & 7) << 4);
      uint2 w2; w2.x = lo; w2.y = hi;
      *(uint2*)((char*)pl + ip * 128 + sw) = w2;
    }

    if (ni & 1) {  // half-tile complete: PV for qi = ni-1, ni
      asm volatile("s_waitcnt lgkmcnt(0)" ::: "memory");
      __builtin_amdgcn_sched_barrier(0);
      const int half = ni >> 1;
#pragma unroll
      for (int q2 = 0; q2 < 2; ++q2) {
        const int qi = half * 2 + q2;
        const int ipr = 16 * q2 + lr;
#pragma unroll
        for (int ks = 0; ks < 2; ++ks) {
          const int bo = 64 * ks + 16 * lg;
          const int swr = bo ^ ((ipr & 7) << 4);
          const bf16x8 pa = *(const bf16x8*)((const char*)pl + ipr * 128 + swr);
#pragma unroll
          for (int nj = 0; nj < 2; ++nj)
            o[qi][nj] = __builtin_amdgcn_mfma_f32_16x16x32_bf16(pa, vfr[nj][ks].v, o[qi][nj], 0, 0, 0);
        }
      }
    }
  }

  // store O[i][d], i = 16*qi + 4*lg + r, d = 16*nj + lr
  const size_t orow = (size_t)b * NWIN;
#pragma unroll
  for (int qi = 0; qi < 4; ++qi)
#pragma unroll
    for (int r = 0; r < 4; ++r) {
      const int i = 16 * qi + 4 * lg + r;
      if (i < NWIN) {
#pragma unroll
        for (int nj = 0; nj < 2; ++nj)
          aout[(orow + i) * C_DIM + h * HD + 16 * nj + lr] = f32_to_bf16(o[qi][nj][r]);
      }
    }
}

// ---------------------------------------------------------------- launch
static const size_t SZ_QKV = (size_t)M_ROWS * QKV_N * 2;
static const size_t SZ_XB  = (size_t)M_ROWS * C_DIM * 2;
static const size_t SZ_WQ  = (size_t)QKV_N * C_DIM * 2;
static const size_t OFF_QKV = 0;
static const size_t OFF_XB  = OFF_QKV + SZ_QKV;   // x_bf16, later reused as attn_out
static const size_t OFF_WQ  = OFF_XB + SZ_XB;
static const size_t OFF_WP  = OFF_WQ + SZ_WQ;

extern "C" void kernel_launch(void* const* d_in, const int* in_sizes, int n_in,
                              void* d_out, int out_size, void* d_ws, size_t ws_size,
                              hipStream_t stream) {
  const float* x      = (const float*)d_in[0];
  const float* mask   = (const float*)d_in[1];
  const float* qkv_w  = (const float*)d_in[2];
  const float* qkv_b  = (const float*)d_in[3];
  const float* proj_w = (const float*)d_in[4];
  const float* proj_b = (const float*)d_in[5];
  const float* rel    = (const float*)d_in[6];
  float* out = (float*)d_out;

  char* ws = (char*)d_ws;
  unsigned short* qkvb = (unsigned short*)(ws + OFF_QKV);
  unsigned short* xb   = (unsigned short*)(ws + OFF_XB);
  unsigned short* wqT  = (unsigned short*)(ws + OFF_WQ);
  unsigned short* wpT  = (unsigned short*)(ws + OFF_WP);
  // bmt (64*16*64*64 f32 = 16.78 MB) lives in d_out scratch space: it is fully
  // consumed by k_attn before the final GEMM overwrites d_out (stream-ordered).
  float* bmt = (float*)d_out;

  k_cvt<<<2048, 256, 0, stream>>>(x, xb, M_ROWS * C_DIM / 4);
  k_transpose_cvt<<<dim3(QKV_N / 32, C_DIM / 32), 256, 0, stream>>>(qkv_w, wqT, C_DIM, QKV_N);
  k_transpose_cvt<<<dim3(C_DIM / 32, C_DIM / 32), 256, 0, stream>>>(proj_w, wpT, C_DIM, C_DIM);
  k_bm<<<(NMASK * NH * 64 * 64) / 256, 256, 0, stream>>>(mask, rel, bmt);

  // qkv = x @ qkv_w + qkv_b   (bf16 out)
  k_gemm<1><<<dim3(QKV_N / 128, M_ROWS / 128), 256, 0, stream>>>(
      xb, wqT, qkv_b, qkvb, M_ROWS, QKV_N, C_DIM);

  // attention -> attn_out (reuses xb region)
  k_attn<<<2048 * NH / 4, 256, 0, stream>>>(qkvb, bmt, xb);

  // out = attn_out @ proj_w + proj_b  (f32 out)
  k_gemm<0><<<dim3(C_DIM / 128, M_ROWS / 128), 256, 0, stream>>>(
      xb, wpT, proj_b, out, M_ROWS, C_DIM, C_DIM);
}

// Round 3
// 570.660 us; speedup vs baseline: 1.2989x; 1.0814x over previous
//
#include <hip/hip_runtime.h>
#include <hip/hip_bf16.h>
#include <stdint.h>

// Problem constants (match setup_inputs)
#define M_ROWS 100352   // 2048 * 49
#define C_DIM  512
#define QKV_N  1536
#define NH     16
#define HD     32
#define NWIN   49       // window tokens (7*7)
#define NMASK  64

typedef __attribute__((ext_vector_type(4))) float        f32x4;
typedef __attribute__((ext_vector_type(8))) short        bf16x8;
typedef __attribute__((ext_vector_type(4))) unsigned int u32x4;

static __device__ __forceinline__ unsigned short f32_to_bf16(float f) {
  union { float f; unsigned int u; } v; v.f = f;
  unsigned int u = v.u;
  return (unsigned short)((u + 0x7FFFu + ((u >> 16) & 1u)) >> 16);  // RNE
}

// global -> LDS direct DMA, 16B per lane. dest = wave-uniform base + lane*16.
static __device__ __forceinline__ void gload_lds16(const void* g, void* l) {
  __builtin_amdgcn_global_load_lds(
      (const __attribute__((address_space(1))) unsigned int*)g,
      (__attribute__((address_space(3))) unsigned int*)l, 16, 0, 0);
}

// ---------------------------------------------------------------- k_cvt
__global__ void k_cvt(const float* __restrict__ in, unsigned short* __restrict__ out, int n4) {
  int i = blockIdx.x * blockDim.x + threadIdx.x;
  int stride = gridDim.x * blockDim.x;
  for (; i < n4; i += stride) {
    float4 v = ((const float4*)in)[i];
    ushort4 o = make_ushort4(f32_to_bf16(v.x), f32_to_bf16(v.y),
                             f32_to_bf16(v.z), f32_to_bf16(v.w));
    ((ushort4*)out)[i] = o;
  }
}

// ------------------------------------------- transpose + convert weights
// in: K x N f32 (row-major), out: N x K bf16 (row-major) == B^T
__global__ void k_transpose_cvt(const float* __restrict__ in, unsigned short* __restrict__ out,
                                int K, int N) {
  __shared__ float t[32][33];
  const int n0 = blockIdx.x * 32, k0 = blockIdx.y * 32;
  const int tx = threadIdx.x & 31, ty = threadIdx.x >> 5;  // 32 x 8
#pragma unroll
  for (int rr = 0; rr < 32; rr += 8)
    t[ty + rr][tx] = in[(size_t)(k0 + ty + rr) * N + n0 + tx];
  __syncthreads();
#pragma unroll
  for (int rr = 0; rr < 32; rr += 8)
    out[(size_t)(n0 + ty + rr) * K + k0 + tx] = f32_to_bf16(t[tx][ty + rr]);
}

// ----------------------------------------- fused bias+mask table (padded)
// bmt[w][h][i][j] (64x16x64x64 f32) = mask[w][i][j] + bias[h][i][j], -1e30 pad.
__global__ __launch_bounds__(256) void k_bm(const float* __restrict__ mask,
                                            const float* __restrict__ rel,
                                            float* __restrict__ bmt) {
  const int idx = blockIdx.x * 256 + threadIdx.x;   // w<<16 | h<<12 | i<<6 | j
  const int j = idx & 63, i = (idx >> 6) & 63, h = (idx >> 12) & 15, w = idx >> 16;
  float v = -1e30f;
  if (i < NWIN && j < NWIN) {
    const int rpi = ((j / 7) - (i / 7) + 6) * 13;
    v = mask[w * (NWIN * NWIN) + i * NWIN + j] + rel[rpi * NH + h];
  }
  bmt[idx] = v;
}

// ------------------------------------------------------------------ GEMM
// C[M,N] = A[M,K](bf16) * BT[N,K]^T(bf16) + bias[N].
// 256x256 tile, BK=64, 512 threads = 8 waves (2Mx4N), 128 KB LDS dbuf.
// LDS layout per operand-tile: subtiled [srow=row/16][scol=col/32][16][32]
// (1024B subtiles), inner byte XOR-swizzled by row bits 3:2 -> ds_read_b128
// column-slice reads are 2-way conflicts (free, m136).  global_load_lds
// writes linearly; source global address carries the inverse permutation
// (col8 ^= lane>>4 bits).  Stage of tile t+1 issued at START of tile t into
// the other buffer; single __syncthreads per tile is the only barrier
// (race-free: no same-buffer write during a tile's reads).
template <int OUT_BF16>
__global__ __launch_bounds__(512, 2) void k_gemm256(const unsigned short* __restrict__ A,
                                                    const unsigned short* __restrict__ BT,
                                                    const float* __restrict__ bias,
                                                    void* __restrict__ Cout,
                                                    int M, int N, int K) {
  __shared__ __align__(16) unsigned short lds[2][2][256 * 64];  // [buf][A|B][...] 128 KB
  const int tid = threadIdx.x;
  const int lane = tid & 63, wave = tid >> 6;
  const int wr = wave >> 2, wc = wave & 3;      // 2 x 4 wave grid
  const int lr = lane & 15, lg = lane >> 4;

  // bijective XCD swizzle (gridDim.x % 8 == 0 for all call sites)
  const int nwg = gridDim.x, q8 = nwg >> 3;
  const int wg = (blockIdx.x & 7) * q8 + (blockIdx.x >> 3);
  const int gx = N >> 8;
  const int bx = wg % gx, by = wg / gx;
  const int m0 = by << 8, n0 = bx << 8;

  // staging: lane -> (row-in-subtile, swizzled 8-col group)
  const int srow_in = lane >> 2;
  const int scol8 = (lane & 3) ^ ((lane >> 4) & 3);   // inverse of read swizzle

  const f32x4 fz = {0.f, 0.f, 0.f, 0.f};
  f32x4 acc[8][4];
#pragma unroll
  for (int i = 0; i < 8; ++i)
#pragma unroll
    for (int j = 0; j < 4; ++j) acc[i][j] = fz;

  const int NT = K >> 6;

  auto stage = [&](int t, int buf) {
    const int k0 = t << 6;
#pragma unroll
    for (int i = 0; i < 4; ++i) {
      const int s = wave * 4 + i;          // subtile 0..31
      const int srow = s >> 1, sc = s & 1;
      const size_t gcol = k0 + sc * 32 + scol8 * 8;
      gload_lds16(A + (size_t)(m0 + srow * 16 + srow_in) * K + gcol,
                  &lds[buf][0][s * 512]);
      gload_lds16(BT + (size_t)(n0 + srow * 16 + srow_in) * K + gcol,
                  &lds[buf][1][s * 512]);
    }
  };

  // swizzled inner offset (ushort units) for frag reads
  const int inner = ((lr * 64 + lg * 16) ^ ((lr & 12) << 2)) >> 1;

  for (int t = 0; t < NT; ++t) {
    const int cur = t & 1;
    if (t == 0) {
      stage(0, 0);
      __syncthreads();                      // drain tile-0 stages
    }
    if (t + 1 < NT) stage(t + 1, cur ^ 1);  // full-tile lookahead into other buf

    const unsigned short* la = lds[cur][0];
    const unsigned short* lb = lds[cur][1];
    bf16x8 bfr[4][2];
#pragma unroll
    for (int nj = 0; nj < 4; ++nj)
#pragma unroll
      for (int ks = 0; ks < 2; ++ks)
        bfr[nj][ks] = *(const bf16x8*)(lb + (((wc * 4 + nj) * 2 + ks) << 9) + inner);
#pragma unroll
    for (int mi = 0; mi < 8; ++mi) {
      bf16x8 af0 = *(const bf16x8*)(la + (((wr * 8 + mi) * 2 + 0) << 9) + inner);
      bf16x8 af1 = *(const bf16x8*)(la + (((wr * 8 + mi) * 2 + 1) << 9) + inner);
      __builtin_amdgcn_s_setprio(1);
#pragma unroll
      for (int nj = 0; nj < 4; ++nj) {
        acc[mi][nj] = __builtin_amdgcn_mfma_f32_16x16x32_bf16(af0, bfr[nj][0], acc[mi][nj], 0, 0, 0);
        acc[mi][nj] = __builtin_amdgcn_mfma_f32_16x16x32_bf16(af1, bfr[nj][1], acc[mi][nj], 0, 0, 0);
      }
      __builtin_amdgcn_s_setprio(0);
    }
    __syncthreads();  // drains t+1 stages (full tile of latency already covered)
  }

  float bv[4];
#pragma unroll
  for (int nj = 0; nj < 4; ++nj) bv[nj] = bias[n0 + wc * 64 + nj * 16 + lr];
#pragma unroll
  for (int mi = 0; mi < 8; ++mi)
#pragma unroll
    for (int nj = 0; nj < 4; ++nj)
#pragma unroll
      for (int r = 0; r < 4; ++r) {
        const int row = m0 + wr * 128 + mi * 16 + 4 * lg + r;
        const int col = n0 + wc * 64 + nj * 16 + lr;
        const float v = acc[mi][nj][r] + bv[nj];
        if (OUT_BF16)
          ((unsigned short*)Cout)[(size_t)row * N + col] = f32_to_bf16(v);
        else
          ((float*)Cout)[(size_t)row * N + col] = v;
      }
}

// ------------------------------------------------------------- attention
// 4 waves/block, one (b,h) per wave, zero barriers (waves independent).
__global__ __launch_bounds__(256) void k_attn(const unsigned short* __restrict__ qkv,
                                              const float* __restrict__ bmt,
                                              unsigned short* __restrict__ aout) {
  const int wave = threadIdx.x >> 6, lane = threadIdx.x & 63;
  const int lr = lane & 15, lg = lane >> 4;
  const int idx = blockIdx.x * 4 + wave;
  const int b = idx >> 4, h = idx & 15, w = b & 63;

  __shared__ __align__(16) unsigned short Pl[4][2048];  // [32 rows][64] swizzled
  __shared__ __align__(16) unsigned short Vt[4][2112];  // V^T, stride 66
  unsigned short* pl = Pl[wave];
  unsigned short* vt = Vt[wave];

  const unsigned short* qp = qkv + (size_t)b * NWIN * QKV_N + h * HD;
  const unsigned short* kp = qp + C_DIM;
  const unsigned short* vp = qp + 2 * C_DIM;

  bf16x8 kf[4], qf[4];
#pragma unroll
  for (int t = 0; t < 4; ++t) {
    kf[t] = *(const bf16x8*)(kp + (size_t)(t * 16 + lr) * QKV_N + lg * 8);
    qf[t] = *(const bf16x8*)(qp + (size_t)(t * 16 + lr) * QKV_N + lg * 8);
  }

  const u32x4 zv = {0u, 0u, 0u, 0u};
#pragma unroll
  for (int c0 = 0; c0 < 4; ++c0) {
    const int c = c0 * 64 + lane;
    const int key = c >> 2, d0 = (c & 3) << 3;
    union { u32x4 v; unsigned short s[8]; } tmp;
    tmp.v = (key < NWIN) ? *(const u32x4*)(vp + (size_t)key * QKV_N + d0) : zv;
#pragma unroll
    for (int jj = 0; jj < 8; ++jj) vt[(d0 + jj) * 66 + key] = tmp.s[jj];
  }

  const f32x4 fz = {0.f, 0.f, 0.f, 0.f};
  f32x4 s[4][4];  // [mi = j-frag][ni = i-frag]
#pragma unroll
  for (int mi = 0; mi < 4; ++mi)
#pragma unroll
    for (int ni = 0; ni < 4; ++ni) s[mi][ni] = fz;
#pragma unroll
  for (int mi = 0; mi < 4; ++mi)
#pragma unroll
    for (int ni = 0; ni < 4; ++ni)
      s[mi][ni] = __builtin_amdgcn_mfma_f32_16x16x32_bf16(kf[mi], qf[ni], s[mi][ni], 0, 0, 0);

  union VU { unsigned int u[4]; bf16x8 v; };
  VU vfr[2][2];  // [nj][ks]
#pragma unroll
  for (int nj = 0; nj < 2; ++nj)
#pragma unroll
    for (int ks = 0; ks < 2; ++ks) {
      const int base = ((16 * nj + lr) * 66 + 32 * ks + 8 * lg) >> 1;
#pragma unroll
      for (int u = 0; u < 4; ++u) vfr[nj][ks].u[u] = ((const unsigned int*)vt)[base + u];
    }

  const float scale = 0.1767766952966369f;  // 32^-0.5
  const float* tbl = bmt + ((size_t)(w * NH + h) << 12);

  f32x4 o[4][2];
#pragma unroll
  for (int qi = 0; qi < 4; ++qi)
#pragma unroll
    for (int nj = 0; nj < 2; ++nj) o[qi][nj] = fz;

#pragma unroll
  for (int ni = 0; ni < 4; ++ni) {
    float v[16];
    float mx = -3e38f;
#pragma unroll
    for (int mi = 0; mi < 4; ++mi) {
      const f32x4 t4 = *(const f32x4*)(tbl + (16 * ni + lr) * 64 + 16 * mi + 4 * lg);
#pragma unroll
      for (int r = 0; r < 4; ++r) {
        v[mi * 4 + r] = fmaf(s[mi][ni][r], scale, t4[r]);
        mx = fmaxf(mx, v[mi * 4 + r]);
      }
    }
    mx = fmaxf(mx, __shfl_xor(mx, 16));
    mx = fmaxf(mx, __shfl_xor(mx, 32));
    float sum = 0.f;
#pragma unroll
    for (int t = 0; t < 16; ++t) {
      v[t] = __expf(v[t] - mx);
      sum += v[t];
    }
    sum += __shfl_xor(sum, 16);
    sum += __shfl_xor(sum, 32);
    const float inv = __builtin_amdgcn_rcpf(sum);

    const int ip = 16 * (ni & 1) + lr;
#pragma unroll
    for (int mi = 0; mi < 4; ++mi) {
      const unsigned int lo = (unsigned int)f32_to_bf16(v[mi * 4 + 0] * inv) |
                              ((unsigned int)f32_to_bf16(v[mi * 4 + 1] * inv) << 16);
      const unsigned int hi = (unsigned int)f32_to_bf16(v[mi * 4 + 2] * inv) |
                              ((unsigned int)f32_to_bf16(v[mi * 4 + 3] * inv) << 16);
      const int byteoff = 32 * mi + 8 * lg;
      const int sw = byteoff ^ ((ip & 7) << 4);
      uint2 w2; w2.x = lo; w2.y = hi;
      *(uint2*)((char*)pl + ip * 128 + sw) = w2;
    }

    if (ni & 1) {
      asm volatile("s_waitcnt lgkmcnt(0)" ::: "memory");
      __builtin_amdgcn_sched_barrier(0);
      const int half = ni >> 1;
#pragma unroll
      for (int q2 = 0; q2 < 2; ++q2) {
        const int qi = half * 2 + q2;
        const int ipr = 16 * q2 + lr;
#pragma unroll
        for (int ks = 0; ks < 2; ++ks) {
          const int bo = 64 * ks + 16 * lg;
          const int swr = bo ^ ((ipr & 7) << 4);
          const bf16x8 pa = *(const bf16x8*)((const char*)pl + ipr * 128 + swr);
#pragma unroll
          for (int nj = 0; nj < 2; ++nj)
            o[qi][nj] = __builtin_amdgcn_mfma_f32_16x16x32_bf16(pa, vfr[nj][ks].v, o[qi][nj], 0, 0, 0);
        }
      }
    }
  }

  const size_t orow = (size_t)b * NWIN;
#pragma unroll
  for (int qi = 0; qi < 4; ++qi)
#pragma unroll
    for (int r = 0; r < 4; ++r) {
      const int i = 16 * qi + 4 * lg + r;
      if (i < NWIN) {
#pragma unroll
        for (int nj = 0; nj < 2; ++nj)
          aout[(orow + i) * C_DIM + h * HD + 16 * nj + lr] = f32_to_bf16(o[qi][nj][r]);
      }
    }
}

// ---------------------------------------------------------------- launch
static const size_t SZ_QKV = (size_t)M_ROWS * QKV_N * 2;
static const size_t SZ_XB  = (size_t)M_ROWS * C_DIM * 2;
static const size_t SZ_WQ  = (size_t)QKV_N * C_DIM * 2;
static const size_t OFF_QKV = 0;
static const size_t OFF_XB  = OFF_QKV + SZ_QKV;   // x_bf16, later reused as attn_out
static const size_t OFF_WQ  = OFF_XB + SZ_XB;
static const size_t OFF_WP  = OFF_WQ + SZ_WQ;

extern "C" void kernel_launch(void* const* d_in, const int* in_sizes, int n_in,
                              void* d_out, int out_size, void* d_ws, size_t ws_size,
                              hipStream_t stream) {
  const float* x      = (const float*)d_in[0];
  const float* mask   = (const float*)d_in[1];
  const float* qkv_w  = (const float*)d_in[2];
  const float* qkv_b  = (const float*)d_in[3];
  const float* proj_w = (const float*)d_in[4];
  const float* proj_b = (const float*)d_in[5];
  const float* rel    = (const float*)d_in[6];
  float* out = (float*)d_out;

  char* ws = (char*)d_ws;
  unsigned short* qkvb = (unsigned short*)(ws + OFF_QKV);
  unsigned short* xb   = (unsigned short*)(ws + OFF_XB);
  unsigned short* wqT  = (unsigned short*)(ws + OFF_WQ);
  unsigned short* wpT  = (unsigned short*)(ws + OFF_WP);
  // bmt (16.78 MB) in d_out scratch: fully consumed by k_attn before final GEMM.
  float* bmt = (float*)d_out;

  k_cvt<<<2048, 256, 0, stream>>>(x, xb, M_ROWS * C_DIM / 4);
  k_transpose_cvt<<<dim3(QKV_N / 32, C_DIM / 32), 256, 0, stream>>>(qkv_w, wqT, C_DIM, QKV_N);
  k_transpose_cvt<<<dim3(C_DIM / 32, C_DIM / 32), 256, 0, stream>>>(proj_w, wpT, C_DIM, C_DIM);
  k_bm<<<(NMASK * NH * 64 * 64) / 256, 256, 0, stream>>>(mask, rel, bmt);

  // qkv = x @ qkv_w + qkv_b   (bf16 out), grid 6*392 = 2352 (%8==0)
  k_gemm256<1><<<(QKV_N / 256) * (M_ROWS / 256), 512, 0, stream>>>(
      xb, wqT, qkv_b, qkvb, M_ROWS, QKV_N, C_DIM);

  // attention -> attn_out (reuses xb region)
  k_attn<<<2048 * NH / 4, 256, 0, stream>>>(qkvb, bmt, xb);

  // out = attn_out @ proj_w + proj_b  (f32 out), grid 2*392 = 784 (%8==0)
  k_gemm256<0><<<(C_DIM / 256) * (M_ROWS / 256), 512, 0, stream>>>(
      xb, wpT, proj_b, out, M_ROWS, C_DIM, C_DIM);
}